// Round 1
// baseline (21930.969 us; speedup 1.0000x reference)
//
#include <hip/hip_runtime.h>

#define N_POI 100000
#define N_EDGE 50000
#define NNZ 3200000
#define D 128

// dst1 = dst2 = src (float4 grid-stride)
__global__ __launch_bounds__(256) void copy2_kernel(const float* __restrict__ src,
                                                    float* __restrict__ dst1,
                                                    float* __restrict__ dst2, int n4) {
    int i = blockIdx.x * 256 + threadIdx.x;
    int stride = gridDim.x * 256;
    const float4* s = (const float4*)src;
    float4* d1 = (float4*)dst1;
    float4* d2 = (float4*)dst2;
    for (; i < n4; i += stride) {
        float4 v = s[i];
        d1[i] = v;
        d2[i] = v;
    }
}

// WdT[j][i] = (Wf1 @ Wpoi)[i][j],  WcT[j][i] = (Wf2 @ Wedge)[i][j]
// Wfus is [128 x 256] row-major; Wf1 = Wfus[:, :128], Wf2 = Wfus[:, 128:].
__global__ __launch_bounds__(128) void wcombo_kernel(const float* __restrict__ Wpoi,
                                                     const float* __restrict__ Wedge,
                                                     const float* __restrict__ Wfus,
                                                     float* __restrict__ WdT,
                                                     float* __restrict__ WcT) {
    int i = blockIdx.x;    // output row of Wd/Wc
    int j = threadIdx.x;   // output col
    float s1 = 0.f, s2 = 0.f;
    for (int k = 0; k < D; ++k) {
        float f1 = Wfus[i * 256 + k];
        float f2 = Wfus[i * 256 + 128 + k];
        s1 += f1 * Wpoi[k * D + j];   // coalesced across lanes
        s2 += f2 * Wedge[k * D + j];
    }
    WdT[j * D + i] = s1;  // store transposed (uncoalesced, 16K elems -> negligible)
    WcT[j * D + i] = s2;
}

// Y[r][c] = sum_k X[r][k] * MT[k][c]   (MT row-major [k][c], i.e. M transposed)
// Block: 256 threads -> 32-row x 128-col tile; thread computes 4x4 register tile.
__global__ __launch_bounds__(256) void dense_xmT(const float* __restrict__ X,
                                                 const float* __restrict__ MT,
                                                 float* __restrict__ Y, int nrows) {
    __shared__ float mt[D * D];    // 64 KB, [k][c] layout
    __shared__ float xs[32 * D];   // 16 KB, [r][k] layout

    // Stage MT once per block: coalesced global float4, conflict-free LDS writes.
    for (int i = threadIdx.x; i < D * D / 4; i += 256)
        ((float4*)mt)[i] = ((const float4*)MT)[i];

    int ntiles = (nrows + 31) >> 5;
    int rg = threadIdx.x >> 5;      // 0..7
    int cg = threadIdx.x & 31;      // 0..31
    int r0 = rg * 4;
    int c0 = cg * 4;

    for (int tile = blockIdx.x; tile < ntiles; tile += gridDim.x) {
        int rbase = tile * 32;
        int nr = min(32, nrows - rbase);
        __syncthreads();  // covers mt staging (iter 1) + xs reuse (later iters)
        for (int i = threadIdx.x; i < nr * 32; i += 256)
            ((float4*)xs)[i] = ((const float4*)(X + (size_t)rbase * D))[i];
        __syncthreads();

        float4 a0 = {0, 0, 0, 0}, a1 = {0, 0, 0, 0}, a2 = {0, 0, 0, 0}, a3 = {0, 0, 0, 0};
#pragma unroll 4
        for (int k = 0; k < D; ++k) {
            float4 m = *(const float4*)&mt[k * D + c0];  // lane-consecutive: minimal pattern
            float x0 = xs[(r0 + 0) * D + k];             // broadcast within row-group
            float x1 = xs[(r0 + 1) * D + k];
            float x2 = xs[(r0 + 2) * D + k];
            float x3 = xs[(r0 + 3) * D + k];
            a0.x += x0 * m.x; a0.y += x0 * m.y; a0.z += x0 * m.z; a0.w += x0 * m.w;
            a1.x += x1 * m.x; a1.y += x1 * m.y; a1.z += x1 * m.z; a1.w += x1 * m.w;
            a2.x += x2 * m.x; a2.y += x2 * m.y; a2.z += x2 * m.z; a2.w += x2 * m.w;
            a3.x += x3 * m.x; a3.y += x3 * m.y; a3.z += x3 * m.z; a3.w += x3 * m.w;
        }
        if (r0 + 0 < nr) *(float4*)&Y[(size_t)(rbase + r0 + 0) * D + c0] = a0;
        if (r0 + 1 < nr) *(float4*)&Y[(size_t)(rbase + r0 + 1) * D + c0] = a1;
        if (r0 + 2 < nr) *(float4*)&Y[(size_t)(rbase + r0 + 2) * D + c0] = a2;
        if (r0 + 3 < nr) *(float4*)&Y[(size_t)(rbase + r0 + 3) * D + c0] = a3;
    }
}

// Y[row] += val * X[col]  (COO scatter, 32 lanes per nnz, float4 gather + 4 HW fp32 atomics)
__global__ __launch_bounds__(256) void spmm_scatter(const int* __restrict__ rows,
                                                    const int* __restrict__ cols,
                                                    const float* __restrict__ vals,
                                                    const float* __restrict__ X,
                                                    float* __restrict__ Y, int nnz) {
    int group = (blockIdx.x * 256 + threadIdx.x) >> 5;
    int lane = threadIdx.x & 31;
    int ngroups = (gridDim.x * 256) >> 5;
    for (int i = group; i < nnz; i += ngroups) {
        int r = rows[i];
        int c = cols[i];
        float v = vals[i];
        float4 x = *(const float4*)&X[(size_t)c * D + lane * 4];
        float* y = &Y[(size_t)r * D + lane * 4];
        unsafeAtomicAdd(y + 0, v * x.x);
        unsafeAtomicAdd(y + 1, v * x.y);
        unsafeAtomicAdd(y + 2, v * x.z);
        unsafeAtomicAdd(y + 3, v * x.w);
    }
}

// sum += w*delta; cur += delta   (float4 grid-stride)
__global__ __launch_bounds__(256) void update_kernel(float* __restrict__ sum,
                                                     float* __restrict__ cur,
                                                     const float* __restrict__ delta,
                                                     float w, int n4) {
    int i = blockIdx.x * 256 + threadIdx.x;
    int stride = gridDim.x * 256;
    float4* s4 = (float4*)sum;
    float4* c4 = (float4*)cur;
    const float4* d4 = (const float4*)delta;
    for (; i < n4; i += stride) {
        float4 d = d4[i];
        float4 s = s4[i];
        s.x += w * d.x; s.y += w * d.y; s.z += w * d.z; s.w += w * d.w;
        s4[i] = s;
        float4 c = c4[i];
        c.x += d.x; c.y += d.y; c.z += d.z; c.w += d.w;
        c4[i] = c;
    }
}

extern "C" void kernel_launch(void* const* d_in, const int* in_sizes, int n_in,
                              void* d_out, int out_size, void* d_ws, size_t ws_size,
                              hipStream_t stream) {
    const float* poi   = (const float*)d_in[0];
    const float* edge  = (const float*)d_in[1];
    const float* Wpoi  = (const float*)d_in[2];
    const float* Wedge = (const float*)d_in[3];
    const float* Wfus  = (const float*)d_in[4];
    const int*   p2e_row = (const int*)d_in[5];
    const int*   p2e_col = (const int*)d_in[6];
    const float* p2e_val = (const float*)d_in[7];
    const int*   e2p_row = (const int*)d_in[8];
    const int*   e2p_col = (const int*)d_in[9];
    const float* e2p_val = (const float*)d_in[10];

    float* out_poi  = (float*)d_out;                    // running poi mean accumulator
    float* out_edge = out_poi + (size_t)N_POI * D;      // running edge mean accumulator

    float* ws    = (float*)d_ws;
    float* A     = ws;                                  // N_POI*D  : xP / prop scratch
    float* B     = A + (size_t)N_POI * D;               // N_EDGE*D : fused
    float* p_cur = B + (size_t)N_EDGE * D;              // N_POI*D
    float* e_cur = p_cur + (size_t)N_POI * D;           // N_EDGE*D
    float* WdT   = e_cur + (size_t)N_EDGE * D;          // D*D
    float* WcT   = WdT + D * D;                         // D*D

    // init: p_cur = out_poi = poi_embs ; e_cur = out_edge = edge_embs
    copy2_kernel<<<2048, 256, 0, stream>>>(poi, p_cur, out_poi, N_POI * D / 4);
    copy2_kernel<<<2048, 256, 0, stream>>>(edge, e_cur, out_edge, N_EDGE * D / 4);
    // folded weight matrices (transposed for the dense kernel's [k][c] staging)
    wcombo_kernel<<<128, 128, 0, stream>>>(Wpoi, Wedge, Wfus, WdT, WcT);

    for (int l = 0; l < 2; ++l) {
        float w = (l == 0) ? (2.f / 3.f) : (1.f / 3.f);
        // A = p_cur @ Wd^T   (= p @ (Wf1 W_poi)^T)
        dense_xmT<<<512, 256, 0, stream>>>(p_cur, WdT, A, N_POI);
        // B = e_cur @ Wc^T   (= e @ (Wf2 W_edge)^T)
        dense_xmT<<<512, 256, 0, stream>>>(e_cur, WcT, B, N_EDGE);
        // B += spmm(p2e, A)  -> B = fused
        spmm_scatter<<<8192, 256, 0, stream>>>(p2e_row, p2e_col, p2e_val, A, B, NNZ);
        // e_cur += fused ; out_edge += w*fused
        update_kernel<<<2048, 256, 0, stream>>>(out_edge, e_cur, B, w, N_EDGE * D / 4);
        // A = spmm(e2p, fused) = prop
        hipMemsetAsync(A, 0, (size_t)N_POI * D * sizeof(float), stream);
        spmm_scatter<<<8192, 256, 0, stream>>>(e2p_row, e2p_col, e2p_val, B, A, NNZ);
        // p_cur += prop ; out_poi += w*prop
        update_kernel<<<2048, 256, 0, stream>>>(out_poi, p_cur, A, w, N_POI * D / 4);
    }
}

// Round 2
// 2288.322 us; speedup vs baseline: 9.5839x; 9.5839x over previous
//
#include <hip/hip_runtime.h>

#define N_POI 100000
#define N_EDGE 50000
#define NNZ 3200000
#define D 128

// dst1 = dst2 = src (float4 grid-stride)
__global__ __launch_bounds__(256) void copy2_kernel(const float* __restrict__ src,
                                                    float* __restrict__ dst1,
                                                    float* __restrict__ dst2, int n4) {
    int i = blockIdx.x * 256 + threadIdx.x;
    int stride = gridDim.x * 256;
    const float4* s = (const float4*)src;
    float4* d1 = (float4*)dst1;
    float4* d2 = (float4*)dst2;
    for (; i < n4; i += stride) {
        float4 v = s[i];
        d1[i] = v;
        d2[i] = v;
    }
}

// WdT[j][i] = (Wf1 @ Wpoi)[i][j],  WcT[j][i] = (Wf2 @ Wedge)[i][j]
__global__ __launch_bounds__(128) void wcombo_kernel(const float* __restrict__ Wpoi,
                                                     const float* __restrict__ Wedge,
                                                     const float* __restrict__ Wfus,
                                                     float* __restrict__ WdT,
                                                     float* __restrict__ WcT) {
    int i = blockIdx.x;
    int j = threadIdx.x;
    float s1 = 0.f, s2 = 0.f;
    for (int k = 0; k < D; ++k) {
        float f1 = Wfus[i * 256 + k];
        float f2 = Wfus[i * 256 + 128 + k];
        s1 += f1 * Wpoi[k * D + j];
        s2 += f2 * Wedge[k * D + j];
    }
    WdT[j * D + i] = s1;
    WcT[j * D + i] = s2;
}

// Y[r][c] = sum_k X[r][k] * MT[k][c]
__global__ __launch_bounds__(256) void dense_xmT(const float* __restrict__ X,
                                                 const float* __restrict__ MT,
                                                 float* __restrict__ Y, int nrows) {
    __shared__ float mt[D * D];
    __shared__ float xs[32 * D];
    for (int i = threadIdx.x; i < D * D / 4; i += 256)
        ((float4*)mt)[i] = ((const float4*)MT)[i];

    int ntiles = (nrows + 31) >> 5;
    int rg = threadIdx.x >> 5;
    int cg = threadIdx.x & 31;
    int r0 = rg * 4;
    int c0 = cg * 4;

    for (int tile = blockIdx.x; tile < ntiles; tile += gridDim.x) {
        int rbase = tile * 32;
        int nr = min(32, nrows - rbase);
        __syncthreads();
        for (int i = threadIdx.x; i < nr * 32; i += 256)
            ((float4*)xs)[i] = ((const float4*)(X + (size_t)rbase * D))[i];
        __syncthreads();

        float4 a0 = {0, 0, 0, 0}, a1 = {0, 0, 0, 0}, a2 = {0, 0, 0, 0}, a3 = {0, 0, 0, 0};
#pragma unroll 4
        for (int k = 0; k < D; ++k) {
            float4 m = *(const float4*)&mt[k * D + c0];
            float x0 = xs[(r0 + 0) * D + k];
            float x1 = xs[(r0 + 1) * D + k];
            float x2 = xs[(r0 + 2) * D + k];
            float x3 = xs[(r0 + 3) * D + k];
            a0.x += x0 * m.x; a0.y += x0 * m.y; a0.z += x0 * m.z; a0.w += x0 * m.w;
            a1.x += x1 * m.x; a1.y += x1 * m.y; a1.z += x1 * m.z; a1.w += x1 * m.w;
            a2.x += x2 * m.x; a2.y += x2 * m.y; a2.z += x2 * m.z; a2.w += x2 * m.w;
            a3.x += x3 * m.x; a3.y += x3 * m.y; a3.z += x3 * m.z; a3.w += x3 * m.w;
        }
        if (r0 + 0 < nr) *(float4*)&Y[(size_t)(rbase + r0 + 0) * D + c0] = a0;
        if (r0 + 1 < nr) *(float4*)&Y[(size_t)(rbase + r0 + 1) * D + c0] = a1;
        if (r0 + 2 < nr) *(float4*)&Y[(size_t)(rbase + r0 + 2) * D + c0] = a2;
        if (r0 + 3 < nr) *(float4*)&Y[(size_t)(rbase + r0 + 3) * D + c0] = a3;
    }
}

// Histogram both matrices' rows into next0/next1 (pre-zeroed).
__global__ __launch_bounds__(256) void hist2_kernel(const int* __restrict__ r0, int* next0,
                                                    const int* __restrict__ r1, int* next1) {
    int i = blockIdx.x * 256 + threadIdx.x;
    int stride = gridDim.x * 256;
    for (int k = i; k < 2 * NNZ; k += stride) {
        if (k < NNZ) atomicAdd(&next0[r0[k]], 1);
        else         atomicAdd(&next1[r1[k - NNZ]], 1);
    }
}

// Exclusive scan (in-place counts -> offsets), one block per matrix.
// Writes row_ptr[0..n] and next[i] = row_ptr[i] (scatter cursor).
__global__ __launch_bounds__(1024) void scan2_kernel(int* next0, int* rp0, int n0,
                                                     int* next1, int* rp1, int n1) {
    int* next = blockIdx.x ? next1 : next0;
    int* rp   = blockIdx.x ? rp1 : rp0;
    int n     = blockIdx.x ? n1 : n0;
    __shared__ int buf[1024];
    __shared__ int s_carry;
    if (threadIdx.x == 0) s_carry = 0;
    __syncthreads();
    for (int base = 0; base < n; base += 1024) {
        int i = base + threadIdx.x;
        int v = (i < n) ? next[i] : 0;
        buf[threadIdx.x] = v;
        __syncthreads();
        for (int off = 1; off < 1024; off <<= 1) {
            int t = (threadIdx.x >= off) ? buf[threadIdx.x - off] : 0;
            __syncthreads();
            buf[threadIdx.x] += t;
            __syncthreads();
        }
        int incl = buf[threadIdx.x];
        int excl = incl - v + s_carry;
        if (i < n) { rp[i] = excl; next[i] = excl; }
        __syncthreads();
        if (threadIdx.x == 0) s_carry += buf[1023];
        __syncthreads();
    }
    if (threadIdx.x == 0) rp[n] = s_carry;
}

// Scatter nnz into CSR order for both matrices.
__global__ __launch_bounds__(256) void scatter2_kernel(
    const int* __restrict__ r0, const int* __restrict__ c0, const float* __restrict__ v0,
    int* next0, int* __restrict__ sc0, float* __restrict__ sv0,
    const int* __restrict__ r1, const int* __restrict__ c1, const float* __restrict__ v1,
    int* next1, int* __restrict__ sc1, float* __restrict__ sv1) {
    int i = blockIdx.x * 256 + threadIdx.x;
    int stride = gridDim.x * 256;
    for (int k = i; k < 2 * NNZ; k += stride) {
        if (k < NNZ) {
            int pos = atomicAdd(&next0[r0[k]], 1);
            sc0[pos] = c0[k];
            sv0[pos] = v0[k];
        } else {
            int k2 = k - NNZ;
            int pos = atomicAdd(&next1[r1[k2]], 1);
            sc1[pos] = c1[k2];
            sv1[pos] = v1[k2];
        }
    }
}

// CSR SpMM with fused epilogue. 32 lanes per row, float4 per lane (128 cols).
// acc = (hasY ? Y[row] : 0) + sum_j val_j * X[col_j]
// if hasY: Y[row] = acc;  cur[row] += acc;  osum[row] += w * acc;
__global__ __launch_bounds__(256) void spmm_csr_fused(
    const int* __restrict__ row_ptr, const int* __restrict__ scol,
    const float* __restrict__ sval, const float* __restrict__ X,
    float* __restrict__ Y, float* __restrict__ cur, float* __restrict__ osum,
    float w, int nrows, int hasY) {
    int row = (blockIdx.x * 256 + threadIdx.x) >> 5;
    int lane = threadIdx.x & 31;
    if (row >= nrows) return;
    int j = row_ptr[row];
    int end = row_ptr[row + 1];
    size_t off = (size_t)row * D + lane * 4;

    float4 acc = {0, 0, 0, 0};
    if (hasY) acc = *(const float4*)&Y[off];

    for (; j + 4 <= end; j += 4) {
        int ca = scol[j], cb = scol[j + 1], cc = scol[j + 2], cd = scol[j + 3];
        float va = sval[j], vb = sval[j + 1], vc = sval[j + 2], vd = sval[j + 3];
        float4 xa = *(const float4*)&X[(size_t)ca * D + lane * 4];
        float4 xb = *(const float4*)&X[(size_t)cb * D + lane * 4];
        float4 xc = *(const float4*)&X[(size_t)cc * D + lane * 4];
        float4 xd = *(const float4*)&X[(size_t)cd * D + lane * 4];
        acc.x += va * xa.x + vb * xb.x + vc * xc.x + vd * xd.x;
        acc.y += va * xa.y + vb * xb.y + vc * xc.y + vd * xd.y;
        acc.z += va * xa.z + vb * xb.z + vc * xc.z + vd * xd.z;
        acc.w += va * xa.w + vb * xb.w + vc * xc.w + vd * xd.w;
    }
    for (; j < end; ++j) {
        int c = scol[j];
        float v = sval[j];
        float4 x = *(const float4*)&X[(size_t)c * D + lane * 4];
        acc.x += v * x.x; acc.y += v * x.y; acc.z += v * x.z; acc.w += v * x.w;
    }

    if (hasY) *(float4*)&Y[off] = acc;
    float4 c4 = *(const float4*)&cur[off];
    c4.x += acc.x; c4.y += acc.y; c4.z += acc.z; c4.w += acc.w;
    *(float4*)&cur[off] = c4;
    float4 o4 = *(const float4*)&osum[off];
    o4.x += w * acc.x; o4.y += w * acc.y; o4.z += w * acc.z; o4.w += w * acc.w;
    *(float4*)&osum[off] = o4;
}

extern "C" void kernel_launch(void* const* d_in, const int* in_sizes, int n_in,
                              void* d_out, int out_size, void* d_ws, size_t ws_size,
                              hipStream_t stream) {
    const float* poi   = (const float*)d_in[0];
    const float* edge  = (const float*)d_in[1];
    const float* Wpoi  = (const float*)d_in[2];
    const float* Wedge = (const float*)d_in[3];
    const float* Wfus  = (const float*)d_in[4];
    const int*   p2e_row = (const int*)d_in[5];
    const int*   p2e_col = (const int*)d_in[6];
    const float* p2e_val = (const float*)d_in[7];
    const int*   e2p_row = (const int*)d_in[8];
    const int*   e2p_col = (const int*)d_in[9];
    const float* e2p_val = (const float*)d_in[10];

    float* out_poi  = (float*)d_out;
    float* out_edge = out_poi + (size_t)N_POI * D;

    char* w = (char*)d_ws;
    float* A      = (float*)w;  w += (size_t)N_POI * D * 4;    // p_cur @ Wd^T
    float* B      = (float*)w;  w += (size_t)N_EDGE * D * 4;   // fused
    float* p_cur  = (float*)w;  w += (size_t)N_POI * D * 4;
    float* e_cur  = (float*)w;  w += (size_t)N_EDGE * D * 4;
    float* WdT    = (float*)w;  w += D * D * 4;
    float* WcT    = (float*)w;  w += D * D * 4;
    int*   rp_p2e = (int*)w;    w += (N_EDGE + 1) * 4;
    int*   nx_p2e = (int*)w;    w += N_EDGE * 4;
    int*   sc_p2e = (int*)w;    w += (size_t)NNZ * 4;
    float* sv_p2e = (float*)w;  w += (size_t)NNZ * 4;
    int*   rp_e2p = (int*)w;    w += (N_POI + 1) * 4;
    int*   nx_e2p = (int*)w;    w += N_POI * 4;
    int*   sc_e2p = (int*)w;    w += (size_t)NNZ * 4;
    float* sv_e2p = (float*)w;  w += (size_t)NNZ * 4;

    // init state + folded weights
    hipMemsetAsync(nx_p2e, 0, N_EDGE * sizeof(int), stream);
    hipMemsetAsync(nx_e2p, 0, N_POI * sizeof(int), stream);
    copy2_kernel<<<2048, 256, 0, stream>>>(poi, p_cur, out_poi, N_POI * D / 4);
    copy2_kernel<<<2048, 256, 0, stream>>>(edge, e_cur, out_edge, N_EDGE * D / 4);
    wcombo_kernel<<<128, 128, 0, stream>>>(Wpoi, Wedge, Wfus, WdT, WcT);

    // build CSR for both sparse matrices (reused across both layers)
    hist2_kernel<<<2048, 256, 0, stream>>>(p2e_row, nx_p2e, e2p_row, nx_e2p);
    scan2_kernel<<<2, 1024, 0, stream>>>(nx_p2e, rp_p2e, N_EDGE, nx_e2p, rp_e2p, N_POI);
    scatter2_kernel<<<2048, 256, 0, stream>>>(p2e_row, p2e_col, p2e_val, nx_p2e, sc_p2e, sv_p2e,
                                              e2p_row, e2p_col, e2p_val, nx_e2p, sc_e2p, sv_e2p);

    for (int l = 0; l < 2; ++l) {
        float wgt = (l == 0) ? (2.f / 3.f) : (1.f / 3.f);
        // A = p_cur @ Wd^T ; B = e_cur @ Wc^T
        dense_xmT<<<512, 256, 0, stream>>>(p_cur, WdT, A, N_POI);
        dense_xmT<<<512, 256, 0, stream>>>(e_cur, WcT, B, N_EDGE);
        // B = fused = B + spmm(p2e, A); e_cur += fused; out_edge += w*fused
        spmm_csr_fused<<<(N_EDGE + 7) / 8, 256, 0, stream>>>(
            rp_p2e, sc_p2e, sv_p2e, A, B, e_cur, out_edge, wgt, N_EDGE, 1);
        // prop = spmm(e2p, fused); p_cur += prop; out_poi += w*prop
        spmm_csr_fused<<<(N_POI + 7) / 8, 256, 0, stream>>>(
            rp_e2p, sc_e2p, sv_e2p, B, nullptr, p_cur, out_poi, wgt, N_POI, 0);
    }
}

// Round 3
// 2150.378 us; speedup vs baseline: 10.1987x; 1.0641x over previous
//
#include <hip/hip_runtime.h>

#define N_POI 100000
#define N_EDGE 50000
#define NNZ 3200000
#define D 128

// dst1 = dst2 = src (float4 grid-stride)
__global__ __launch_bounds__(256) void copy2_kernel(const float* __restrict__ src,
                                                    float* __restrict__ dst1,
                                                    float* __restrict__ dst2, int n4) {
    int i = blockIdx.x * 256 + threadIdx.x;
    int stride = gridDim.x * 256;
    const float4* s = (const float4*)src;
    float4* d1 = (float4*)dst1;
    float4* d2 = (float4*)dst2;
    for (; i < n4; i += stride) {
        float4 v = s[i];
        d1[i] = v;
        d2[i] = v;
    }
}

// WdT[j][i] = (Wf1 @ Wpoi)[i][j],  WcT[j][i] = (Wf2 @ Wedge)[i][j]
__global__ __launch_bounds__(128) void wcombo_kernel(const float* __restrict__ Wpoi,
                                                     const float* __restrict__ Wedge,
                                                     const float* __restrict__ Wfus,
                                                     float* __restrict__ WdT,
                                                     float* __restrict__ WcT) {
    int i = blockIdx.x;
    int j = threadIdx.x;
    float s1 = 0.f, s2 = 0.f;
    for (int k = 0; k < D; ++k) {
        float f1 = Wfus[i * 256 + k];
        float f2 = Wfus[i * 256 + 128 + k];
        s1 += f1 * Wpoi[k * D + j];
        s2 += f2 * Wedge[k * D + j];
    }
    WdT[j * D + i] = s1;
    WcT[j * D + i] = s2;
}

// Y[r][c] = sum_k X[r][k] * MT[k][c]
__global__ __launch_bounds__(256) void dense_xmT(const float* __restrict__ X,
                                                 const float* __restrict__ MT,
                                                 float* __restrict__ Y, int nrows) {
    __shared__ float mt[D * D];
    __shared__ float xs[32 * D];
    for (int i = threadIdx.x; i < D * D / 4; i += 256)
        ((float4*)mt)[i] = ((const float4*)MT)[i];

    int ntiles = (nrows + 31) >> 5;
    int rg = threadIdx.x >> 5;
    int cg = threadIdx.x & 31;
    int r0 = rg * 4;
    int c0 = cg * 4;

    for (int tile = blockIdx.x; tile < ntiles; tile += gridDim.x) {
        int rbase = tile * 32;
        int nr = min(32, nrows - rbase);
        __syncthreads();
        for (int i = threadIdx.x; i < nr * 32; i += 256)
            ((float4*)xs)[i] = ((const float4*)(X + (size_t)rbase * D))[i];
        __syncthreads();

        float4 a0 = {0, 0, 0, 0}, a1 = {0, 0, 0, 0}, a2 = {0, 0, 0, 0}, a3 = {0, 0, 0, 0};
#pragma unroll 4
        for (int k = 0; k < D; ++k) {
            float4 m = *(const float4*)&mt[k * D + c0];
            float x0 = xs[(r0 + 0) * D + k];
            float x1 = xs[(r0 + 1) * D + k];
            float x2 = xs[(r0 + 2) * D + k];
            float x3 = xs[(r0 + 3) * D + k];
            a0.x += x0 * m.x; a0.y += x0 * m.y; a0.z += x0 * m.z; a0.w += x0 * m.w;
            a1.x += x1 * m.x; a1.y += x1 * m.y; a1.z += x1 * m.z; a1.w += x1 * m.w;
            a2.x += x2 * m.x; a2.y += x2 * m.y; a2.z += x2 * m.z; a2.w += x2 * m.w;
            a3.x += x3 * m.x; a3.y += x3 * m.y; a3.z += x3 * m.z; a3.w += x3 * m.w;
        }
        if (r0 + 0 < nr) *(float4*)&Y[(size_t)(rbase + r0 + 0) * D + c0] = a0;
        if (r0 + 1 < nr) *(float4*)&Y[(size_t)(rbase + r0 + 1) * D + c0] = a1;
        if (r0 + 2 < nr) *(float4*)&Y[(size_t)(rbase + r0 + 2) * D + c0] = a2;
        if (r0 + 3 < nr) *(float4*)&Y[(size_t)(rbase + r0 + 3) * D + c0] = a3;
    }
}

// Histogram both matrices' rows into next0/next1 (pre-zeroed).
__global__ __launch_bounds__(256) void hist2_kernel(const int* __restrict__ r0, int* next0,
                                                    const int* __restrict__ r1, int* next1) {
    int i = blockIdx.x * 256 + threadIdx.x;
    int stride = gridDim.x * 256;
    for (int k = i; k < 2 * NNZ; k += stride) {
        if (k < NNZ) atomicAdd(&next0[r0[k]], 1);
        else         atomicAdd(&next1[r1[k - NNZ]], 1);
    }
}

// ---- 3-phase multi-block exclusive scan (1024 elems/block) ----
__global__ __launch_bounds__(256) void scan_partials(const int* __restrict__ counts, int n,
                                                     int* __restrict__ partials) {
    __shared__ int red[256];
    int i0 = blockIdx.x * 1024 + threadIdx.x * 4;
    int s = 0;
#pragma unroll
    for (int t = 0; t < 4; ++t)
        if (i0 + t < n) s += counts[i0 + t];
    red[threadIdx.x] = s;
    __syncthreads();
    for (int off = 128; off > 0; off >>= 1) {
        if (threadIdx.x < off) red[threadIdx.x] += red[threadIdx.x + off];
        __syncthreads();
    }
    if (threadIdx.x == 0) partials[blockIdx.x] = red[0];
}

// single block, exclusive scan of nb (<=128) partials in place
__global__ __launch_bounds__(128) void scan_top(int* partials, int nb) {
    __shared__ int buf[128];
    int v = (threadIdx.x < nb) ? partials[threadIdx.x] : 0;
    buf[threadIdx.x] = v;
    __syncthreads();
    for (int off = 1; off < 128; off <<= 1) {
        int t = (threadIdx.x >= off) ? buf[threadIdx.x - off] : 0;
        __syncthreads();
        buf[threadIdx.x] += t;
        __syncthreads();
    }
    if (threadIdx.x < nb) partials[threadIdx.x] = buf[threadIdx.x] - v;
}

__global__ __launch_bounds__(256) void scan_apply(const int* __restrict__ counts, int n,
                                                  const int* __restrict__ partials,
                                                  int* __restrict__ rp, int* __restrict__ next,
                                                  int total) {
    __shared__ int buf[256];
    int i0 = blockIdx.x * 1024 + threadIdx.x * 4;
    int v[4];
#pragma unroll
    for (int t = 0; t < 4; ++t) v[t] = (i0 + t < n) ? counts[i0 + t] : 0;
    int s = v[0] + v[1] + v[2] + v[3];
    buf[threadIdx.x] = s;
    __syncthreads();
    for (int off = 1; off < 256; off <<= 1) {
        int t = (threadIdx.x >= off) ? buf[threadIdx.x - off] : 0;
        __syncthreads();
        buf[threadIdx.x] += t;
        __syncthreads();
    }
    int excl = buf[threadIdx.x] - s + partials[blockIdx.x];
#pragma unroll
    for (int t = 0; t < 4; ++t) {
        if (i0 + t < n) { rp[i0 + t] = excl; next[i0 + t] = excl; }
        excl += v[t];
    }
    if (blockIdx.x == 0 && threadIdx.x == 0) rp[n] = total;
}

// Scatter nnz into CSR order; (col,val) packed in one int2 -> one 8B store per nnz.
__global__ __launch_bounds__(256) void scatter2_kernel(
    const int* __restrict__ r0, const int* __restrict__ c0, const float* __restrict__ v0,
    int* next0, int2* __restrict__ cv0,
    const int* __restrict__ r1, const int* __restrict__ c1, const float* __restrict__ v1,
    int* next1, int2* __restrict__ cv1) {
    int i = blockIdx.x * 256 + threadIdx.x;
    int stride = gridDim.x * 256;
    for (int k = i; k < 2 * NNZ; k += stride) {
        if (k < NNZ) {
            int pos = atomicAdd(&next0[r0[k]], 1);
            cv0[pos] = make_int2(c0[k], __float_as_int(v0[k]));
        } else {
            int k2 = k - NNZ;
            int pos = atomicAdd(&next1[r1[k2]], 1);
            cv1[pos] = make_int2(c1[k2], __float_as_int(v1[k2]));
        }
    }
}

// CSR SpMM with fused epilogue. 32 lanes per row, float4 per lane (128 cols).
__global__ __launch_bounds__(256) void spmm_csr_fused(
    const int* __restrict__ row_ptr, const int2* __restrict__ cv,
    const float* __restrict__ X,
    float* __restrict__ Y, float* __restrict__ cur, float* __restrict__ osum,
    float w, int nrows, int hasY) {
    int row = (blockIdx.x * 256 + threadIdx.x) >> 5;
    int lane = threadIdx.x & 31;
    if (row >= nrows) return;
    int j = row_ptr[row];
    int end = row_ptr[row + 1];
    size_t off = (size_t)row * D + lane * 4;

    float4 acc = {0, 0, 0, 0};
    if (hasY) acc = *(const float4*)&Y[off];

    for (; j + 4 <= end; j += 4) {
        int2 a = cv[j], b = cv[j + 1], c = cv[j + 2], d = cv[j + 3];
        float va = __int_as_float(a.y), vb = __int_as_float(b.y);
        float vc = __int_as_float(c.y), vd = __int_as_float(d.y);
        float4 xa = *(const float4*)&X[(size_t)a.x * D + lane * 4];
        float4 xb = *(const float4*)&X[(size_t)b.x * D + lane * 4];
        float4 xc = *(const float4*)&X[(size_t)c.x * D + lane * 4];
        float4 xd = *(const float4*)&X[(size_t)d.x * D + lane * 4];
        acc.x += va * xa.x + vb * xb.x + vc * xc.x + vd * xd.x;
        acc.y += va * xa.y + vb * xb.y + vc * xc.y + vd * xd.y;
        acc.z += va * xa.z + vb * xb.z + vc * xc.z + vd * xd.z;
        acc.w += va * xa.w + vb * xb.w + vc * xc.w + vd * xd.w;
    }
    for (; j < end; ++j) {
        int2 a = cv[j];
        float v = __int_as_float(a.y);
        float4 x = *(const float4*)&X[(size_t)a.x * D + lane * 4];
        acc.x += v * x.x; acc.y += v * x.y; acc.z += v * x.z; acc.w += v * x.w;
    }

    if (hasY) *(float4*)&Y[off] = acc;
    float4 c4 = *(const float4*)&cur[off];
    c4.x += acc.x; c4.y += acc.y; c4.z += acc.z; c4.w += acc.w;
    *(float4*)&cur[off] = c4;
    float4 o4 = *(const float4*)&osum[off];
    o4.x += w * acc.x; o4.y += w * acc.y; o4.z += w * acc.z; o4.w += w * acc.w;
    *(float4*)&osum[off] = o4;
}

extern "C" void kernel_launch(void* const* d_in, const int* in_sizes, int n_in,
                              void* d_out, int out_size, void* d_ws, size_t ws_size,
                              hipStream_t stream) {
    const float* poi   = (const float*)d_in[0];
    const float* edge  = (const float*)d_in[1];
    const float* Wpoi  = (const float*)d_in[2];
    const float* Wedge = (const float*)d_in[3];
    const float* Wfus  = (const float*)d_in[4];
    const int*   p2e_row = (const int*)d_in[5];
    const int*   p2e_col = (const int*)d_in[6];
    const float* p2e_val = (const float*)d_in[7];
    const int*   e2p_row = (const int*)d_in[8];
    const int*   e2p_col = (const int*)d_in[9];
    const float* e2p_val = (const float*)d_in[10];

    float* out_poi  = (float*)d_out;
    float* out_edge = out_poi + (size_t)N_POI * D;

    char* w = (char*)d_ws;
    float* A      = (float*)w;  w += (size_t)N_POI * D * 4;    // p_cur @ Wd^T / prop scratch
    float* B      = (float*)w;  w += (size_t)N_EDGE * D * 4;   // fused
    float* p_cur  = (float*)w;  w += (size_t)N_POI * D * 4;
    float* e_cur  = (float*)w;  w += (size_t)N_EDGE * D * 4;
    float* WdT    = (float*)w;  w += D * D * 4;
    float* WcT    = (float*)w;  w += D * D * 4;
    int*   rp_p2e = (int*)w;    w += ((N_EDGE + 1) * 4 + 15) / 16 * 16;
    int*   nx_p2e = (int*)w;    w += (N_EDGE * 4 + 15) / 16 * 16;
    int*   rp_e2p = (int*)w;    w += ((N_POI + 1) * 4 + 15) / 16 * 16;
    int*   nx_e2p = (int*)w;    w += (N_POI * 4 + 15) / 16 * 16;
    int*   part0  = (int*)w;    w += 128 * 4;
    int*   part1  = (int*)w;    w += 128 * 4;
    int2*  cv_p2e = (int2*)w;   w += (size_t)NNZ * 8;
    int2*  cv_e2p = (int2*)w;   w += (size_t)NNZ * 8;

    const int NB0 = (N_EDGE + 1023) / 1024;  // 49
    const int NB1 = (N_POI + 1023) / 1024;   // 98

    // init state + folded weights
    hipMemsetAsync(nx_p2e, 0, N_EDGE * sizeof(int), stream);
    hipMemsetAsync(nx_e2p, 0, N_POI * sizeof(int), stream);
    copy2_kernel<<<2048, 256, 0, stream>>>(poi, p_cur, out_poi, N_POI * D / 4);
    copy2_kernel<<<2048, 256, 0, stream>>>(edge, e_cur, out_edge, N_EDGE * D / 4);
    wcombo_kernel<<<128, 128, 0, stream>>>(Wpoi, Wedge, Wfus, WdT, WcT);

    // build CSR for both sparse matrices (reused across both layers)
    hist2_kernel<<<2048, 256, 0, stream>>>(p2e_row, nx_p2e, e2p_row, nx_e2p);
    scan_partials<<<NB0, 256, 0, stream>>>(nx_p2e, N_EDGE, part0);
    scan_partials<<<NB1, 256, 0, stream>>>(nx_e2p, N_POI, part1);
    scan_top<<<1, 128, 0, stream>>>(part0, NB0);
    scan_top<<<1, 128, 0, stream>>>(part1, NB1);
    scan_apply<<<NB0, 256, 0, stream>>>(nx_p2e, N_EDGE, part0, rp_p2e, nx_p2e, NNZ);
    scan_apply<<<NB1, 256, 0, stream>>>(nx_e2p, N_POI, part1, rp_e2p, nx_e2p, NNZ);
    scatter2_kernel<<<2048, 256, 0, stream>>>(p2e_row, p2e_col, p2e_val, nx_p2e, cv_p2e,
                                              e2p_row, e2p_col, e2p_val, nx_e2p, cv_e2p);

    for (int l = 0; l < 2; ++l) {
        float wgt = (l == 0) ? (2.f / 3.f) : (1.f / 3.f);
        // A = p_cur @ Wd^T ; B = e_cur @ Wc^T
        dense_xmT<<<512, 256, 0, stream>>>(p_cur, WdT, A, N_POI);
        dense_xmT<<<512, 256, 0, stream>>>(e_cur, WcT, B, N_EDGE);
        // B = fused = B + spmm(p2e, A); e_cur += fused; out_edge += w*fused
        spmm_csr_fused<<<(N_EDGE + 7) / 8, 256, 0, stream>>>(
            rp_p2e, cv_p2e, A, B, e_cur, out_edge, wgt, N_EDGE, 1);
        // prop = spmm(e2p, fused); p_cur += prop; out_poi += w*prop
        spmm_csr_fused<<<(N_POI + 7) / 8, 256, 0, stream>>>(
            rp_e2p, cv_e2p, B, nullptr, p_cur, out_poi, wgt, N_POI, 0);
    }
}

// Round 4
// 1539.058 us; speedup vs baseline: 14.2496x; 1.3972x over previous
//
#include <hip/hip_runtime.h>

#define N_POI 100000
#define N_EDGE 50000
#define NNZ 3200000
#define D 128

__device__ inline unsigned short f2bf(float f) {  // RN-even fp32->bf16
    unsigned int u = __float_as_uint(f);
    return (unsigned short)((u + 0x7fff + ((u >> 16) & 1)) >> 16);
}
__device__ inline float bf2f(unsigned short u) {
    return __uint_as_float(((unsigned int)u) << 16);
}
__device__ inline int2 nt_int2(const int2* p) {
    unsigned long long u = __builtin_nontemporal_load((const unsigned long long*)p);
    int2 r; r.x = (int)(unsigned)(u & 0xffffffffull); r.y = (int)(unsigned)(u >> 32);
    return r;
}

// dst1 = dst2 = src (float4 grid-stride)
__global__ __launch_bounds__(256) void copy2_kernel(const float* __restrict__ src,
                                                    float* __restrict__ dst1,
                                                    float* __restrict__ dst2, int n4) {
    int i = blockIdx.x * 256 + threadIdx.x;
    int stride = gridDim.x * 256;
    const float4* s = (const float4*)src;
    float4* d1 = (float4*)dst1;
    float4* d2 = (float4*)dst2;
    for (; i < n4; i += stride) {
        float4 v = s[i];
        d1[i] = v;
        d2[i] = v;
    }
}

// WdT[j][i] = (Wf1 @ Wpoi)[i][j],  WcT[j][i] = (Wf2 @ Wedge)[i][j]
__global__ __launch_bounds__(128) void wcombo_kernel(const float* __restrict__ Wpoi,
                                                     const float* __restrict__ Wedge,
                                                     const float* __restrict__ Wfus,
                                                     float* __restrict__ WdT,
                                                     float* __restrict__ WcT) {
    int i = blockIdx.x;
    int j = threadIdx.x;
    float s1 = 0.f, s2 = 0.f;
    for (int k = 0; k < D; ++k) {
        float f1 = Wfus[i * 256 + k];
        float f2 = Wfus[i * 256 + 128 + k];
        s1 += f1 * Wpoi[k * D + j];
        s2 += f2 * Wedge[k * D + j];
    }
    WdT[j * D + i] = s1;
    WcT[j * D + i] = s2;
}

// Y[r][c] = sum_k X[r][k] * MT[k][c].  BF16OUT: Y is bf16 (ushort), else fp32.
template <bool BF16OUT>
__global__ __launch_bounds__(256) void dense_xmT(const float* __restrict__ X,
                                                 const float* __restrict__ MT,
                                                 void* __restrict__ Yv, int nrows) {
    __shared__ float mt[D * D];
    __shared__ float xs[32 * D];
    for (int i = threadIdx.x; i < D * D / 4; i += 256)
        ((float4*)mt)[i] = ((const float4*)MT)[i];

    int ntiles = (nrows + 31) >> 5;
    int rg = threadIdx.x >> 5;
    int cg = threadIdx.x & 31;
    int r0 = rg * 4;
    int c0 = cg * 4;

    for (int tile = blockIdx.x; tile < ntiles; tile += gridDim.x) {
        int rbase = tile * 32;
        int nr = min(32, nrows - rbase);
        __syncthreads();
        for (int i = threadIdx.x; i < nr * 32; i += 256)
            ((float4*)xs)[i] = ((const float4*)(X + (size_t)rbase * D))[i];
        __syncthreads();

        float4 a0 = {0, 0, 0, 0}, a1 = {0, 0, 0, 0}, a2 = {0, 0, 0, 0}, a3 = {0, 0, 0, 0};
#pragma unroll 4
        for (int k = 0; k < D; ++k) {
            float4 m = *(const float4*)&mt[k * D + c0];
            float x0 = xs[(r0 + 0) * D + k];
            float x1 = xs[(r0 + 1) * D + k];
            float x2 = xs[(r0 + 2) * D + k];
            float x3 = xs[(r0 + 3) * D + k];
            a0.x += x0 * m.x; a0.y += x0 * m.y; a0.z += x0 * m.z; a0.w += x0 * m.w;
            a1.x += x1 * m.x; a1.y += x1 * m.y; a1.z += x1 * m.z; a1.w += x1 * m.w;
            a2.x += x2 * m.x; a2.y += x2 * m.y; a2.z += x2 * m.z; a2.w += x2 * m.w;
            a3.x += x3 * m.x; a3.y += x3 * m.y; a3.z += x3 * m.z; a3.w += x3 * m.w;
        }
        float4 accs[4] = {a0, a1, a2, a3};
#pragma unroll
        for (int t = 0; t < 4; ++t) {
            if (r0 + t < nr) {
                size_t off = (size_t)(rbase + r0 + t) * D + c0;
                if (BF16OUT) {
                    ushort4 u;
                    u.x = f2bf(accs[t].x); u.y = f2bf(accs[t].y);
                    u.z = f2bf(accs[t].z); u.w = f2bf(accs[t].w);
                    *(ushort4*)&((unsigned short*)Yv)[off] = u;
                } else {
                    *(float4*)&((float*)Yv)[off] = accs[t];
                }
            }
        }
    }
}

// Histogram both matrices' rows into next0/next1 (pre-zeroed).
__global__ __launch_bounds__(256) void hist2_kernel(const int* __restrict__ r0, int* next0,
                                                    const int* __restrict__ r1, int* next1) {
    int i = blockIdx.x * 256 + threadIdx.x;
    int stride = gridDim.x * 256;
    for (int k = i; k < 2 * NNZ; k += stride) {
        if (k < NNZ) atomicAdd(&next0[__builtin_nontemporal_load(&r0[k])], 1);
        else         atomicAdd(&next1[__builtin_nontemporal_load(&r1[k - NNZ])], 1);
    }
}

// ---- 3-phase multi-block exclusive scan (1024 elems/block) ----
__global__ __launch_bounds__(256) void scan_partials(const int* __restrict__ counts, int n,
                                                     int* __restrict__ partials) {
    __shared__ int red[256];
    int i0 = blockIdx.x * 1024 + threadIdx.x * 4;
    int s = 0;
#pragma unroll
    for (int t = 0; t < 4; ++t)
        if (i0 + t < n) s += counts[i0 + t];
    red[threadIdx.x] = s;
    __syncthreads();
    for (int off = 128; off > 0; off >>= 1) {
        if (threadIdx.x < off) red[threadIdx.x] += red[threadIdx.x + off];
        __syncthreads();
    }
    if (threadIdx.x == 0) partials[blockIdx.x] = red[0];
}

__global__ __launch_bounds__(128) void scan_top(int* partials, int nb) {
    __shared__ int buf[128];
    int v = (threadIdx.x < nb) ? partials[threadIdx.x] : 0;
    buf[threadIdx.x] = v;
    __syncthreads();
    for (int off = 1; off < 128; off <<= 1) {
        int t = (threadIdx.x >= off) ? buf[threadIdx.x - off] : 0;
        __syncthreads();
        buf[threadIdx.x] += t;
        __syncthreads();
    }
    if (threadIdx.x < nb) partials[threadIdx.x] = buf[threadIdx.x] - v;
}

__global__ __launch_bounds__(256) void scan_apply(const int* __restrict__ counts, int n,
                                                  const int* __restrict__ partials,
                                                  int* __restrict__ rp, int* __restrict__ next,
                                                  int total) {
    __shared__ int buf[256];
    int i0 = blockIdx.x * 1024 + threadIdx.x * 4;
    int v[4];
#pragma unroll
    for (int t = 0; t < 4; ++t) v[t] = (i0 + t < n) ? counts[i0 + t] : 0;
    int s = v[0] + v[1] + v[2] + v[3];
    buf[threadIdx.x] = s;
    __syncthreads();
    for (int off = 1; off < 256; off <<= 1) {
        int t = (threadIdx.x >= off) ? buf[threadIdx.x - off] : 0;
        __syncthreads();
        buf[threadIdx.x] += t;
        __syncthreads();
    }
    int excl = buf[threadIdx.x] - s + partials[blockIdx.x];
#pragma unroll
    for (int t = 0; t < 4; ++t) {
        if (i0 + t < n) { rp[i0 + t] = excl; next[i0 + t] = excl; }
        excl += v[t];
    }
    if (blockIdx.x == 0 && threadIdx.x == 0) rp[n] = total;
}

// XCD-sharded CSR scatter. blockIdx&7 -> shard -> contiguous row range; with
// round-robin block->XCD dispatch each XCD's cv stores stay in a ~3.2MB region
// that fits its 4MiB L2 -> full-line writebacks instead of 1 line per 8B store.
__global__ __launch_bounds__(256) void scatter_shard(const int* __restrict__ r,
                                                     const int* __restrict__ c,
                                                     const float* __restrict__ v,
                                                     int* next, int2* __restrict__ cv,
                                                     int rows_per_shard) {
    int shard = blockIdx.x & 7;
    int lo = shard * rows_per_shard;
    int hi = lo + rows_per_shard;
    int blk = blockIdx.x >> 3;
    int nblk = gridDim.x >> 3;
    int i = blk * 256 + threadIdx.x;
    int stride = nblk * 256;
    for (int k = i; k < NNZ; k += stride) {
        int row = __builtin_nontemporal_load(&r[k]);
        if (row >= lo && row < hi) {
            int pos = atomicAdd(&next[row], 1);
            int col = __builtin_nontemporal_load(&c[k]);
            float val = __builtin_nontemporal_load(&v[k]);
            cv[pos] = make_int2(col, __float_as_int(val));
        }
    }
}

// CSR SpMM, bf16 gather payload, fp32 accumulate, fused epilogue.
// acc = (Yinit? Yinit[row] : 0) + sum val * bf16(X[col]);
// cur[row] += acc; osum[row] += w*acc; if (outb) outb[row] = bf16(acc).
__global__ __launch_bounds__(256) void spmm_csr_bf16(
    const int* __restrict__ row_ptr, const int2* __restrict__ cv,
    const unsigned short* __restrict__ Xb, const float* __restrict__ Yinit,
    float* __restrict__ cur, float* __restrict__ osum, unsigned short* __restrict__ outb,
    float w, int nrows) {
    int row = (blockIdx.x * 256 + threadIdx.x) >> 5;
    int lane = threadIdx.x & 31;
    if (row >= nrows) return;
    int j = row_ptr[row];
    int end = row_ptr[row + 1];
    size_t off = (size_t)row * D + lane * 4;

    float4 acc = {0, 0, 0, 0};
    if (Yinit) acc = *(const float4*)&Yinit[off];

    for (; j + 4 <= end; j += 4) {
        int2 a = nt_int2(&cv[j]);
        int2 b = nt_int2(&cv[j + 1]);
        int2 cc = nt_int2(&cv[j + 2]);
        int2 dd = nt_int2(&cv[j + 3]);
        ushort4 xa = *(const ushort4*)&Xb[(size_t)a.x * D + lane * 4];
        ushort4 xb = *(const ushort4*)&Xb[(size_t)b.x * D + lane * 4];
        ushort4 xc = *(const ushort4*)&Xb[(size_t)cc.x * D + lane * 4];
        ushort4 xd = *(const ushort4*)&Xb[(size_t)dd.x * D + lane * 4];
        float va = __int_as_float(a.y), vb = __int_as_float(b.y);
        float vc = __int_as_float(cc.y), vd = __int_as_float(dd.y);
        acc.x += va * bf2f(xa.x) + vb * bf2f(xb.x) + vc * bf2f(xc.x) + vd * bf2f(xd.x);
        acc.y += va * bf2f(xa.y) + vb * bf2f(xb.y) + vc * bf2f(xc.y) + vd * bf2f(xd.y);
        acc.z += va * bf2f(xa.z) + vb * bf2f(xb.z) + vc * bf2f(xc.z) + vd * bf2f(xd.z);
        acc.w += va * bf2f(xa.w) + vb * bf2f(xb.w) + vc * bf2f(xc.w) + vd * bf2f(xd.w);
    }
    for (; j < end; ++j) {
        int2 a = nt_int2(&cv[j]);
        float va = __int_as_float(a.y);
        ushort4 xa = *(const ushort4*)&Xb[(size_t)a.x * D + lane * 4];
        acc.x += va * bf2f(xa.x); acc.y += va * bf2f(xa.y);
        acc.z += va * bf2f(xa.z); acc.w += va * bf2f(xa.w);
    }

    float4 c4 = *(const float4*)&cur[off];
    c4.x += acc.x; c4.y += acc.y; c4.z += acc.z; c4.w += acc.w;
    *(float4*)&cur[off] = c4;
    float4 o4 = *(const float4*)&osum[off];
    o4.x += w * acc.x; o4.y += w * acc.y; o4.z += w * acc.z; o4.w += w * acc.w;
    *(float4*)&osum[off] = o4;
    if (outb) {
        ushort4 u;
        u.x = f2bf(acc.x); u.y = f2bf(acc.y); u.z = f2bf(acc.z); u.w = f2bf(acc.w);
        *(ushort4*)&outb[off] = u;
    }
}

extern "C" void kernel_launch(void* const* d_in, const int* in_sizes, int n_in,
                              void* d_out, int out_size, void* d_ws, size_t ws_size,
                              hipStream_t stream) {
    const float* poi   = (const float*)d_in[0];
    const float* edge  = (const float*)d_in[1];
    const float* Wpoi  = (const float*)d_in[2];
    const float* Wedge = (const float*)d_in[3];
    const float* Wfus  = (const float*)d_in[4];
    const int*   p2e_row = (const int*)d_in[5];
    const int*   p2e_col = (const int*)d_in[6];
    const float* p2e_val = (const float*)d_in[7];
    const int*   e2p_row = (const int*)d_in[8];
    const int*   e2p_col = (const int*)d_in[9];
    const float* e2p_val = (const float*)d_in[10];

    float* out_poi  = (float*)d_out;
    float* out_edge = out_poi + (size_t)N_POI * D;

    char* w = (char*)d_ws;
    unsigned short* Ab = (unsigned short*)w; w += (size_t)N_POI * D * 2;   // bf16(p@Wd^T)
    float* B           = (float*)w;          w += (size_t)N_EDGE * D * 4;  // e@Wc^T (spmm1 init)
    unsigned short* Bb = (unsigned short*)w; w += (size_t)N_EDGE * D * 2;  // bf16(fused)
    float* p_cur       = (float*)w;          w += (size_t)N_POI * D * 4;
    float* e_cur       = (float*)w;          w += (size_t)N_EDGE * D * 4;
    float* WdT         = (float*)w;          w += D * D * 4;
    float* WcT         = (float*)w;          w += D * D * 4;
    int*   rp_p2e      = (int*)w;            w += ((N_EDGE + 1) * 4 + 15) / 16 * 16;
    int*   nx_p2e      = (int*)w;            w += (N_EDGE * 4 + 15) / 16 * 16;
    int*   rp_e2p      = (int*)w;            w += ((N_POI + 1) * 4 + 15) / 16 * 16;
    int*   nx_e2p      = (int*)w;            w += (N_POI * 4 + 15) / 16 * 16;
    int*   part0       = (int*)w;            w += 128 * 4;
    int*   part1       = (int*)w;            w += 128 * 4;
    int2*  cv_p2e      = (int2*)w;           w += (size_t)NNZ * 8;
    int2*  cv_e2p      = (int2*)w;           w += (size_t)NNZ * 8;

    const int NB0 = (N_EDGE + 1023) / 1024;  // 49
    const int NB1 = (N_POI + 1023) / 1024;   // 98

    hipMemsetAsync(nx_p2e, 0, N_EDGE * sizeof(int), stream);
    hipMemsetAsync(nx_e2p, 0, N_POI * sizeof(int), stream);
    copy2_kernel<<<2048, 256, 0, stream>>>(poi, p_cur, out_poi, N_POI * D / 4);
    copy2_kernel<<<2048, 256, 0, stream>>>(edge, e_cur, out_edge, N_EDGE * D / 4);
    wcombo_kernel<<<128, 128, 0, stream>>>(Wpoi, Wedge, Wfus, WdT, WcT);

    // CSR build (reused across layers)
    hist2_kernel<<<2048, 256, 0, stream>>>(p2e_row, nx_p2e, e2p_row, nx_e2p);
    scan_partials<<<NB0, 256, 0, stream>>>(nx_p2e, N_EDGE, part0);
    scan_partials<<<NB1, 256, 0, stream>>>(nx_e2p, N_POI, part1);
    scan_top<<<1, 128, 0, stream>>>(part0, NB0);
    scan_top<<<1, 128, 0, stream>>>(part1, NB1);
    scan_apply<<<NB0, 256, 0, stream>>>(nx_p2e, N_EDGE, part0, rp_p2e, nx_p2e, NNZ);
    scan_apply<<<NB1, 256, 0, stream>>>(nx_e2p, N_POI, part1, rp_e2p, nx_e2p, NNZ);
    // two sequential sharded scatters so each keeps <=3.2MB/XCD of cv resident in L2
    scatter_shard<<<2048, 256, 0, stream>>>(p2e_row, p2e_col, p2e_val, nx_p2e, cv_p2e,
                                            N_EDGE / 8);
    scatter_shard<<<2048, 256, 0, stream>>>(e2p_row, e2p_col, e2p_val, nx_e2p, cv_e2p,
                                            N_POI / 8);

    for (int l = 0; l < 2; ++l) {
        float wgt = (l == 0) ? (2.f / 3.f) : (1.f / 3.f);
        dense_xmT<true><<<512, 256, 0, stream>>>(p_cur, WdT, Ab, N_POI);
        dense_xmT<false><<<512, 256, 0, stream>>>(e_cur, WcT, B, N_EDGE);
        // fused = B + spmm(p2e, Ab); e_cur += fused; out_edge += w*fused; Bb = bf16(fused)
        spmm_csr_bf16<<<(N_EDGE + 7) / 8, 256, 0, stream>>>(
            rp_p2e, cv_p2e, Ab, B, e_cur, out_edge, Bb, wgt, N_EDGE);
        // prop = spmm(e2p, Bb); p_cur += prop; out_poi += w*prop
        spmm_csr_bf16<<<(N_POI + 7) / 8, 256, 0, stream>>>(
            rp_e2p, cv_e2p, Bb, nullptr, p_cur, out_poi, nullptr, wgt, N_POI);
    }
}